// Round 7
// baseline (15108.060 us; speedup 1.0000x reference)
//
#include <hip/hip_runtime.h>
#include <hip/hip_bf16.h>
#include <stdint.h>

#define TT 2048
#define BB 32
#define II 256
#define HH 256
#define NP 16          // participating workgroups (grid size; w = blockIdx.x)
#define HW 16          // h-dims per participant (HH/NP)
#define LROW 264       // h_lds row stride in shorts (528B)
#define XROW 272       // x_lds row stride in shorts (544B)
#define ROUNDS_MAX (1 << 20)   // poll bounds: fail-slow (visible), never silent
#define SENT_STRIDE 16         // sentinels 64B apart (one line each, no false sharing)

// ws layout (dword offsets):
//   [0 .. 256)       16 sentinels at w*SENT_STRIDE, init 0xFFFFFFFF
//   [1024 .. 17408)  xch payload: 2 * BB*HH tagged dwords (64 KB), init 0xAA

typedef __attribute__((ext_vector_type(8))) short short8;
typedef __attribute__((ext_vector_type(4))) float floatx4;

__device__ __forceinline__ short bf16r(float f) {
    __hip_bfloat16 b = __float2bfloat16(f);
    return *reinterpret_cast<short*>(&b);
}

// Exchange primitives — round-4/6 proven: relaxed atomics at AGENT scope
// (compiler emits memory-model-correct cache bits; exchange at the LLC
// coherence point). Tag travels IN the payload dword -> data is its own
// flag; stale reads fail the tag and re-poll. Round 7 adds a per-WG
// SENTINEL as a cheap spin target; it is only a HINT — the tagged read
// remains the ground truth, so sentinel semantics cannot corrupt results.
__device__ __forceinline__ void st_xch(unsigned* p, unsigned v) {
    __hip_atomic_store(p, v, __ATOMIC_RELAXED, __HIP_MEMORY_SCOPE_AGENT);
}
__device__ __forceinline__ void st_rel(unsigned* p, unsigned v) {
    __hip_atomic_store(p, v, __ATOMIC_RELEASE, __HIP_MEMORY_SCOPE_AGENT);
}
__device__ __forceinline__ unsigned ld_xch(const unsigned* p) {
    return __hip_atomic_load(p, __ATOMIC_RELAXED, __HIP_MEMORY_SCOPE_AGENT);
}

// 16 WGs, one per worker w = blockIdx.x. Worker w owns h-dims [w*16,w*16+16)
// -> gate cols {g*256+w*16+j}. Weights register-stationary. x staged to LDS
// as bf16 one step ahead (loads issued pre-poll, cvt+write post-gather so the
// HBM latency hides under the producer wait). h exchange: tagged dwords
// double-buffered by t&1, sentinel-gated spin (wave0/lane<16 only).
__global__ __launch_bounds__(256, 1)
void rev_lstm_kernel(const float* __restrict__ x,
                     const float* __restrict__ h0,
                     const float* __restrict__ c0,
                     const float* __restrict__ Wih,
                     const float* __restrict__ Whh,
                     const float* __restrict__ bih,
                     const float* __restrict__ bhh,
                     float* __restrict__ out,
                     unsigned int* __restrict__ ws)
{
    unsigned* sent = ws;                // 16 sentinels, 64B apart
    unsigned* xch  = ws + 1024;         // 2 * BB*HH tagged dwords (64 KB)

    __shared__ __align__(16) short h_lds[BB * LROW];
    __shared__ __align__(16) short x_lds[2][BB * XROW];   // bf16 x-tile dbuf
    __shared__ float gates_lds[4 * BB * HW];   // [gate][b][j]

    const int tid = threadIdx.x;
    const int w   = blockIdx.x;         // worker id, no election

    const int wid  = tid >> 6;          // wave id == gate id (i,f,g,o)
    const int lane = tid & 63;
    const int l15  = lane & 15;
    const int quad = lane >> 4;

    // staging mapping: thread owns (row = tid>>3, k-seg = tid&7 -> 32 k's)
    const int srow = tid >> 3, sseg = tid & 7;

    // ---- stationary weight B-fragments (B[k][n]: n=lane&15 -> col, k=quad*8+j)
    const int col = wid * HH + w * HW + l15;
    short8 wihf[8], whhf[8];
#pragma unroll
    for (int kt = 0; kt < 8; ++kt) {
        const int k0 = kt * 32 + quad * 8;
        const float* pi = Wih + (size_t)col * II + k0;
        const float* ph = Whh + (size_t)col * HH + k0;
        short8 a, b;
#pragma unroll
        for (int j = 0; j < 8; ++j) { a[j] = bf16r(pi[j]); b[j] = bf16r(ph[j]); }
        wihf[kt] = a; whhf[kt] = b;
    }
    const float bias = bih[col] + bhh[col];

    // ---- c state fp32; thread owns (b=jb, j=jj) and (b=jb+16, j=jj)
    const int jb = tid >> 4;
    const int jj = tid & 15;
    float creg0 = c0[(size_t)jb * HH + w * HW + jj];
    float creg1 = c0[(size_t)(jb + 16) * HH + w * HW + jj];

    // ---- prefill h_lds with h0 (fp32 -> bf16)
    const int pb = tid >> 3, pseg = tid & 7;     // poll/gather mapping
    {
        const float* src = h0 + (size_t)pb * HH + pseg * 32;
#pragma unroll
        for (int u = 0; u < 32; ++u) h_lds[pb * LROW + pseg * 32 + u] = bf16r(src[u]);
    }

    // ---- prologue: stage x_{TT-1} into x_lds[0]
    {
        const float* src = x + (size_t)(TT - 1) * (BB * II) + srow * II + sseg * 32;
        float4 f[8];
#pragma unroll
        for (int q = 0; q < 8; ++q) f[q] = *reinterpret_cast<const float4*>(src + q * 4);
        short* dst = &x_lds[0][srow * XROW + sseg * 32];
#pragma unroll
        for (int qq = 0; qq < 4; ++qq) {
            short8 s;
            s[0]=bf16r(f[2*qq].x);   s[1]=bf16r(f[2*qq].y);
            s[2]=bf16r(f[2*qq].z);   s[3]=bf16r(f[2*qq].w);
            s[4]=bf16r(f[2*qq+1].x); s[5]=bf16r(f[2*qq+1].y);
            s[6]=bf16r(f[2*qq+1].z); s[7]=bf16r(f[2*qq+1].w);
            *reinterpret_cast<short8*>(dst + qq * 8) = s;
        }
    }
    __syncthreads();

    int cur = 0;
    for (int t = TT - 1; t >= 0; --t) {
        // ---- 1. x-part from LDS: 16 ds_read_b128 + 16 MFMAs
        floatx4 acc0 = {bias, bias, bias, bias};
        floatx4 acc1 = {bias, bias, bias, bias};
        const short* xb = &x_lds[cur][0];
#pragma unroll
        for (int kt = 0; kt < 8; ++kt) {
            const int off = kt * 32 + quad * 8;
            short8 a = *reinterpret_cast<const short8*>(xb + l15 * XROW + off);
            short8 b = *reinterpret_cast<const short8*>(xb + (l15 + 16) * XROW + off);
            acc0 = __builtin_amdgcn_mfma_f32_16x16x32_bf16(a, wihf[kt], acc0, 0, 0, 0);
            acc1 = __builtin_amdgcn_mfma_f32_16x16x32_bf16(b, wihf[kt], acc1, 0, 0, 0);
        }

        // ---- 1b-issue. x_{t-1} loads ISSUED here; consumed after the gather
        // barrier, so their HBM/LLC latency hides under the producer wait.
        float4 f[8];
        if (t > 0) {
            const float* src = x + (size_t)(t - 1) * (BB * II) + srow * II + sseg * 32;
#pragma unroll
            for (int q = 0; q < 8; ++q) f[q] = *reinterpret_cast<const float4*>(src + q * 4);
        }

        // ---- 2. wait for h_{t+1}: sentinel hint spin (wave0 lanes<16, 64B/round
        // instead of 512KB/round grid-wide), then the PROVEN tagged read once.
        if (t != TT - 1) {
            const unsigned wantS = (unsigned)(t + 1);
            if (tid < 64) {
                int srounds = 0;
                bool sok;
                do {
                    unsigned sv = (lane < 16) ? ld_xch(sent + lane * SENT_STRIDE) : 0u;
                    sok = __all((lane < 16) ? (sv <= wantS) : 1);
                } while (!sok && ++srounds < ROUNDS_MAX);
            }
            __syncthreads();

            const unsigned want = ((unsigned)(t + 1)) << 16;
            const unsigned* base = xch + (((unsigned)(t + 1)) & 1u) * (BB * HH)
                                       + pb * HH + pseg * 32;
            unsigned v[32];
            int rounds = 0;
            bool ok;
            do {                                 // ground truth: tag check
#pragma unroll
                for (int i = 0; i < 32; ++i) v[i] = ld_xch(base + i);
                ok = true;
#pragma unroll
                for (int i = 0; i < 32; ++i)
                    ok = ok && ((v[i] & 0xFFFF0000u) == want);
            } while (!ok && ++rounds < ROUNDS_MAX);

            // bf16 payloads -> LDS (packed pairs, 4x b128 writes)
#pragma unroll
            for (int q2 = 0; q2 < 4; ++q2) {
                uint4 d;
                d.x = (v[q2*8+0] & 0xFFFFu) | (v[q2*8+1] << 16);
                d.y = (v[q2*8+2] & 0xFFFFu) | (v[q2*8+3] << 16);
                d.z = (v[q2*8+4] & 0xFFFFu) | (v[q2*8+5] << 16);
                d.w = (v[q2*8+6] & 0xFFFFu) | (v[q2*8+7] << 16);
                *reinterpret_cast<uint4*>(h_lds + pb * LROW + pseg * 32 + q2 * 8) = d;
            }
            __syncthreads();
        }

        // ---- 1b-finish. cvt + LDS-write x_{t-1} (overlaps h-MFMA wave issue;
        // buffer safety: reads of x_lds[cur^1] happen next iter, after this
        // iter's gates barrier).
        if (t > 0) {
            short* dst = &x_lds[cur ^ 1][srow * XROW + sseg * 32];
#pragma unroll
            for (int qq = 0; qq < 4; ++qq) {
                short8 s;
                s[0]=bf16r(f[2*qq].x);   s[1]=bf16r(f[2*qq].y);
                s[2]=bf16r(f[2*qq].z);   s[3]=bf16r(f[2*qq].w);
                s[4]=bf16r(f[2*qq+1].x); s[5]=bf16r(f[2*qq+1].y);
                s[6]=bf16r(f[2*qq+1].z); s[7]=bf16r(f[2*qq+1].w);
                *reinterpret_cast<short8*>(dst + qq * 8) = s;
            }
        }

        // ---- 3. recurrent MFMAs: += h@Whh^T
#pragma unroll
        for (int kt = 0; kt < 8; ++kt) {
            const int off = kt * 32 + quad * 8;
            short8 ha0 = *reinterpret_cast<const short8*>(h_lds + l15 * LROW + off);
            short8 ha1 = *reinterpret_cast<const short8*>(h_lds + (l15 + 16) * LROW + off);
            acc0 = __builtin_amdgcn_mfma_f32_16x16x32_bf16(ha0, whhf[kt], acc0, 0, 0, 0);
            acc1 = __builtin_amdgcn_mfma_f32_16x16x32_bf16(ha1, whhf[kt], acc1, 0, 0, 0);
        }

        // ---- 4. accumulators -> LDS (C/D layout: col=lane&15, row=quad*4+r)
#pragma unroll
        for (int r = 0; r < 4; ++r) {
            gates_lds[(wid * BB + quad * 4 + r) * HW + l15]      = acc0[r];
            gates_lds[(wid * BB + 16 + quad * 4 + r) * HW + l15] = acc1[r];
        }
        __syncthreads();

        // ---- 5. cell; tagged h -> exchange (critical path first)
        float hval[2];
#pragma unroll
        for (int n = 0; n < 2; ++n) {
            const int b = jb + n * 16;
            const float ig = gates_lds[(0 * BB + b) * HW + jj];
            const float fg = gates_lds[(1 * BB + b) * HW + jj];
            const float gg = gates_lds[(2 * BB + b) * HW + jj];
            const float og = gates_lds[(3 * BB + b) * HW + jj];
            const float is = 1.f / (1.f + __expf(-ig));
            const float fs = 1.f / (1.f + __expf(-fg));
            const float gt = 1.f - 2.f / (1.f + __expf(2.f * gg));
            const float os = 1.f / (1.f + __expf(-og));
            const float cprev = (n == 0) ? creg0 : creg1;
            const float c  = fs * cprev + is * gt;
            const float h  = os * (1.f - 2.f / (1.f + __expf(2.f * c)));
            if (n == 0) creg0 = c; else creg1 = c;
            hval[n] = h;

            const unsigned pack = (((unsigned)t) << 16)
                                | (unsigned)(unsigned short)bf16r(h);
            st_xch(xch + ((unsigned)t & 1u) * (BB * HH) + (size_t)b * HH + w * HW + jj,
                   pack);
        }

        // ---- 5b. publish sentinel: __syncthreads drains vmcnt(0) for every
        // thread's payload stores before the barrier, then one release store.
        // (Hint only — consumers still verify tags.)
        if (t > 0) {
            __syncthreads();
            if (tid == 0) st_rel(sent + w * SENT_STRIDE, (unsigned)t);
        }

        // ---- 6. ys -> out (nontemporal), off the exchange critical path
#pragma unroll
        for (int n = 0; n < 2; ++n) {
            const int b = jb + n * 16;
            __builtin_nontemporal_store(hval[n], out + (size_t)t * (BB * HH)
                                                     + (size_t)b * HH + w * HW + jj);
            if (t == 0) {
                out[(size_t)TT * (BB * HH) + (size_t)b * HH + w * HW + jj] = hval[n];
                out[(size_t)TT * (BB * HH) + (BB * HH) + (size_t)b * HH + w * HW + jj]
                    = (n == 0) ? creg0 : creg1;
            }
        }

        cur ^= 1;
    }
}

extern "C" void kernel_launch(void* const* d_in, const int* in_sizes, int n_in,
                              void* d_out, int out_size, void* d_ws, size_t ws_size,
                              hipStream_t stream) {
    const float* x   = (const float*)d_in[0];
    const float* h0  = (const float*)d_in[1];
    const float* c0  = (const float*)d_in[2];
    const float* Wih = (const float*)d_in[3];
    const float* Whh = (const float*)d_in[4];
    const float* bih = (const float*)d_in[5];
    const float* bhh = (const float*)d_in[6];
    float* out = (float*)d_out;
    unsigned int* ws = (unsigned int*)d_ws;

    // sentinels init 0xFFFFFFFF (> any step, unsigned) over ws[0..1024);
    // xch tag bytes 0xAAAA never match a step tag (t+1 <= 2048).
    hipMemsetAsync(ws, 0xFF, 1024 * sizeof(unsigned int), stream);
    hipMemsetAsync(ws + 1024, 0xAA, 2 * BB * HH * sizeof(unsigned int), stream);
    hipLaunchKernelGGL(rev_lstm_kernel, dim3(NP), dim3(256), 0, stream,
                       x, h0, c0, Wih, Whh, bih, bhh, out, ws);
}

// Round 8
// 9877.532 us; speedup vs baseline: 1.5295x; 1.5295x over previous
//
#include <hip/hip_runtime.h>
#include <hip/hip_bf16.h>
#include <stdint.h>

#define TT 2048
#define BB 32
#define II 256
#define HH 256
#define NP 16          // participating workgroups (grid size; w = blockIdx.x)
#define HW 16          // h-dims per participant (HH/NP)
#define LROW 264       // h_lds row stride in shorts (528B)
#define XROW 272       // x_lds row stride in shorts (544B)
#define ROUNDS_MAX (1 << 20)   // poll bound: fail-slow (visible), never silent

typedef __attribute__((ext_vector_type(8))) short short8;
typedef __attribute__((ext_vector_type(4))) float floatx4;

__device__ __forceinline__ short bf16r(float f) {
    __hip_bfloat16 b = __float2bfloat16(f);
    return *reinterpret_cast<short*>(&b);
}

// Exchange primitives.
// Stores: compiler atomics at AGENT scope (proven rounds 4/6) — emit the
// memory-model-correct cache bits for device-wide visibility at the LLC.
// Loads (round-8 change): round 6 polled via 32 SCALAR atomic loads; side-
// effecting atomics get conservative codegen (narrow loads, interleaved
// waits) -> one poll round cost several LLC latencies. Replace with 8
// inline-asm dwordx4 loads carrying sc1 ONLY (= agent scope, reads the LLC
// coherence point; round-5 lesson: sc0+sc1 = system scope = bypasses LLC ->
// stale). One batched issue + one vmcnt wait = one LLC latency per round.
// Tag-in-dword remains ground truth: a stale read fails the tag, re-polls.
__device__ __forceinline__ void st_xch(unsigned* p, unsigned v) {
    __hip_atomic_store(p, v, __ATOMIC_RELAXED, __HIP_MEMORY_SCOPE_AGENT);
}
__device__ __forceinline__ uint4 ld4_agent(const unsigned* p) {
    uint4 r;
    asm volatile("global_load_dwordx4 %0, %1, off sc1" : "=v"(r) : "v"(p) : "memory");
    return r;
}
__device__ __forceinline__ void waitvm0() {
    asm volatile("s_waitcnt vmcnt(0)" ::: "memory");
}

// 16 WGs, one per worker w = blockIdx.x. Worker w owns h-dims [w*16,w*16+16)
// -> gate cols {g*256+w*16+j}. Weights register-stationary. x staged to LDS
// as bf16 one step ahead (double-buffered). h exchange: fused {t<<16|bf16(h)}
// dwords, double-buffered by t&1 — data IS the flag.
__global__ __launch_bounds__(256, 1)
void rev_lstm_kernel(const float* __restrict__ x,
                     const float* __restrict__ h0,
                     const float* __restrict__ c0,
                     const float* __restrict__ Wih,
                     const float* __restrict__ Whh,
                     const float* __restrict__ bih,
                     const float* __restrict__ bhh,
                     float* __restrict__ out,
                     unsigned int* __restrict__ ws)
{
    unsigned* xch = ws + 16;            // 2 * BB*HH tagged dwords (64 KB)

    __shared__ __align__(16) short h_lds[BB * LROW];
    __shared__ __align__(16) short x_lds[2][BB * XROW];   // bf16 x-tile dbuf
    __shared__ float gates_lds[4 * BB * HW];   // [gate][b][j]

    const int tid = threadIdx.x;
    const int w   = blockIdx.x;         // worker id, no election

    const int wid  = tid >> 6;          // wave id == gate id (i,f,g,o)
    const int lane = tid & 63;
    const int l15  = lane & 15;
    const int quad = lane >> 4;

    // staging mapping: thread owns (row = tid>>3, k-seg = tid&7 -> 32 k's)
    const int srow = tid >> 3, sseg = tid & 7;

    // ---- stationary weight B-fragments (B[k][n]: n=lane&15 -> col, k=quad*8+j)
    const int col = wid * HH + w * HW + l15;
    short8 wihf[8], whhf[8];
#pragma unroll
    for (int kt = 0; kt < 8; ++kt) {
        const int k0 = kt * 32 + quad * 8;
        const float* pi = Wih + (size_t)col * II + k0;
        const float* ph = Whh + (size_t)col * HH + k0;
        short8 a, b;
#pragma unroll
        for (int j = 0; j < 8; ++j) { a[j] = bf16r(pi[j]); b[j] = bf16r(ph[j]); }
        wihf[kt] = a; whhf[kt] = b;
    }
    const float bias = bih[col] + bhh[col];

    // ---- c state fp32; thread owns (b=jb, j=jj) and (b=jb+16, j=jj)
    const int jb = tid >> 4;
    const int jj = tid & 15;
    float creg0 = c0[(size_t)jb * HH + w * HW + jj];
    float creg1 = c0[(size_t)(jb + 16) * HH + w * HW + jj];

    // ---- prefill h_lds with h0 (fp32 -> bf16)
    const int pb = tid >> 3, pseg = tid & 7;     // poll/gather mapping
    {
        const float* src = h0 + (size_t)pb * HH + pseg * 32;
#pragma unroll
        for (int u = 0; u < 32; ++u) h_lds[pb * LROW + pseg * 32 + u] = bf16r(src[u]);
    }

    // ---- prologue: stage x_{TT-1} into x_lds[0]
    {
        const float* src = x + (size_t)(TT - 1) * (BB * II) + srow * II + sseg * 32;
        float4 f[8];
#pragma unroll
        for (int q = 0; q < 8; ++q) f[q] = *reinterpret_cast<const float4*>(src + q * 4);
        short* dst = &x_lds[0][srow * XROW + sseg * 32];
#pragma unroll
        for (int qq = 0; qq < 4; ++qq) {
            short8 s;
            s[0]=bf16r(f[2*qq].x);   s[1]=bf16r(f[2*qq].y);
            s[2]=bf16r(f[2*qq].z);   s[3]=bf16r(f[2*qq].w);
            s[4]=bf16r(f[2*qq+1].x); s[5]=bf16r(f[2*qq+1].y);
            s[6]=bf16r(f[2*qq+1].z); s[7]=bf16r(f[2*qq+1].w);
            *reinterpret_cast<short8*>(dst + qq * 8) = s;
        }
    }
    __syncthreads();

    int cur = 0;
    for (int t = TT - 1; t >= 0; --t) {
        // ---- 1. x-part from LDS: 16 ds_read_b128 + 16 MFMAs (no cvt)
        floatx4 acc0 = {bias, bias, bias, bias};
        floatx4 acc1 = {bias, bias, bias, bias};
        const short* xb = &x_lds[cur][0];
#pragma unroll
        for (int kt = 0; kt < 8; ++kt) {
            const int off = kt * 32 + quad * 8;
            short8 a = *reinterpret_cast<const short8*>(xb + l15 * XROW + off);
            short8 b = *reinterpret_cast<const short8*>(xb + (l15 + 16) * XROW + off);
            acc0 = __builtin_amdgcn_mfma_f32_16x16x32_bf16(a, wihf[kt], acc0, 0, 0, 0);
            acc1 = __builtin_amdgcn_mfma_f32_16x16x32_bf16(b, wihf[kt], acc1, 0, 0, 0);
        }

        // ---- 1b-issue. x_{t-1} loads ISSUED here; the first poll round's
        // vmcnt(0) drains them, so their HBM latency hides under the wait.
        float4 f[8];
        if (t > 0) {
            const float* src = x + (size_t)(t - 1) * (BB * II) + srow * II + sseg * 32;
#pragma unroll
            for (int q = 0; q < 8; ++q) f[q] = *reinterpret_cast<const float4*>(src + q * 4);
        }

        // ---- 2. poll tagged h_{t+1}: 8x dwordx4 sc1 (agent/LLC), one vmcnt
        // wait per round; data IS the flag.
        if (t != TT - 1) {
            const unsigned want = ((unsigned)(t + 1)) << 16;
            const unsigned* base = xch + (((unsigned)(t + 1)) & 1u) * (BB * HH)
                                       + pb * HH + pseg * 32;
            unsigned v[32];
            int rounds = 0;
            bool ok;
            do {
                uint4 q[8];
#pragma unroll
                for (int i = 0; i < 8; ++i) q[i] = ld4_agent(base + i * 4);
                waitvm0();
#pragma unroll
                for (int i = 0; i < 8; ++i) {
                    v[i*4+0] = q[i].x; v[i*4+1] = q[i].y;
                    v[i*4+2] = q[i].z; v[i*4+3] = q[i].w;
                }
                ok = true;
#pragma unroll
                for (int i = 0; i < 32; ++i)
                    ok = ok && ((v[i] & 0xFFFF0000u) == want);
            } while (!ok && ++rounds < ROUNDS_MAX);

            // bf16 payloads -> LDS (packed pairs, 4x b128 writes)
#pragma unroll
            for (int q2 = 0; q2 < 4; ++q2) {
                uint4 d;
                d.x = (v[q2*8+0] & 0xFFFFu) | (v[q2*8+1] << 16);
                d.y = (v[q2*8+2] & 0xFFFFu) | (v[q2*8+3] << 16);
                d.z = (v[q2*8+4] & 0xFFFFu) | (v[q2*8+5] << 16);
                d.w = (v[q2*8+6] & 0xFFFFu) | (v[q2*8+7] << 16);
                *reinterpret_cast<uint4*>(h_lds + pb * LROW + pseg * 32 + q2 * 8) = d;
            }
            __syncthreads();
        }

        // ---- 1b-finish. cvt + LDS-write x_{t-1} (overlaps h-MFMA issue;
        // buffer safety: x_lds[cur^1] reads happen next iter, after this
        // iter's gates barrier).
        if (t > 0) {
            short* dst = &x_lds[cur ^ 1][srow * XROW + sseg * 32];
#pragma unroll
            for (int qq = 0; qq < 4; ++qq) {
                short8 s;
                s[0]=bf16r(f[2*qq].x);   s[1]=bf16r(f[2*qq].y);
                s[2]=bf16r(f[2*qq].z);   s[3]=bf16r(f[2*qq].w);
                s[4]=bf16r(f[2*qq+1].x); s[5]=bf16r(f[2*qq+1].y);
                s[6]=bf16r(f[2*qq+1].z); s[7]=bf16r(f[2*qq+1].w);
                *reinterpret_cast<short8*>(dst + qq * 8) = s;
            }
        }

        // ---- 3. recurrent MFMAs: += h@Whh^T
#pragma unroll
        for (int kt = 0; kt < 8; ++kt) {
            const int off = kt * 32 + quad * 8;
            short8 ha0 = *reinterpret_cast<const short8*>(h_lds + l15 * LROW + off);
            short8 ha1 = *reinterpret_cast<const short8*>(h_lds + (l15 + 16) * LROW + off);
            acc0 = __builtin_amdgcn_mfma_f32_16x16x32_bf16(ha0, whhf[kt], acc0, 0, 0, 0);
            acc1 = __builtin_amdgcn_mfma_f32_16x16x32_bf16(ha1, whhf[kt], acc1, 0, 0, 0);
        }

        // ---- 4. accumulators -> LDS (C/D layout: col=lane&15, row=quad*4+r)
#pragma unroll
        for (int r = 0; r < 4; ++r) {
            gates_lds[(wid * BB + quad * 4 + r) * HW + l15]      = acc0[r];
            gates_lds[(wid * BB + 16 + quad * 4 + r) * HW + l15] = acc1[r];
        }
        __syncthreads();

        // ---- 5. cell; tagged h -> exchange (critical), ys -> out (nontemporal)
        float hval[2];
#pragma unroll
        for (int n = 0; n < 2; ++n) {
            const int b = jb + n * 16;
            const float ig = gates_lds[(0 * BB + b) * HW + jj];
            const float fg = gates_lds[(1 * BB + b) * HW + jj];
            const float gg = gates_lds[(2 * BB + b) * HW + jj];
            const float og = gates_lds[(3 * BB + b) * HW + jj];
            const float is = 1.f / (1.f + __expf(-ig));
            const float fs = 1.f / (1.f + __expf(-fg));
            const float gt = 1.f - 2.f / (1.f + __expf(2.f * gg));
            const float os = 1.f / (1.f + __expf(-og));
            const float cprev = (n == 0) ? creg0 : creg1;
            const float c  = fs * cprev + is * gt;
            const float h  = os * (1.f - 2.f / (1.f + __expf(2.f * c)));
            if (n == 0) creg0 = c; else creg1 = c;
            hval[n] = h;

            const unsigned pack = (((unsigned)t) << 16)
                                | (unsigned)(unsigned short)bf16r(h);
            st_xch(xch + ((unsigned)t & 1u) * (BB * HH) + (size_t)b * HH + w * HW + jj,
                   pack);
        }

        // ---- 6. ys -> out (nontemporal), off the exchange critical path
#pragma unroll
        for (int n = 0; n < 2; ++n) {
            const int b = jb + n * 16;
            __builtin_nontemporal_store(hval[n], out + (size_t)t * (BB * HH)
                                                     + (size_t)b * HH + w * HW + jj);
            if (t == 0) {
                out[(size_t)TT * (BB * HH) + (size_t)b * HH + w * HW + jj] = hval[n];
                out[(size_t)TT * (BB * HH) + (BB * HH) + (size_t)b * HH + w * HW + jj]
                    = (n == 0) ? creg0 : creg1;
            }
        }

        cur ^= 1;
        // no trailing barrier: next iteration's LDS writes are fenced by its own
        // post-gather barrier; gates_lds reads complete before anyone passes it.
    }
}

extern "C" void kernel_launch(void* const* d_in, const int* in_sizes, int n_in,
                              void* d_out, int out_size, void* d_ws, size_t ws_size,
                              hipStream_t stream) {
    const float* x   = (const float*)d_in[0];
    const float* h0  = (const float*)d_in[1];
    const float* c0  = (const float*)d_in[2];
    const float* Wih = (const float*)d_in[3];
    const float* Whh = (const float*)d_in[4];
    const float* bih = (const float*)d_in[5];
    const float* bhh = (const float*)d_in[6];
    float* out = (float*)d_out;
    unsigned int* ws = (unsigned int*)d_ws;

    // xch tag bytes 0xAAAA never match a step tag (t+1 <= 2048 < 0xAAAA).
    hipMemsetAsync(ws, 0, 64, stream);
    hipMemsetAsync(ws + 16, 0xAA, 2 * BB * HH * sizeof(unsigned int), stream);
    hipLaunchKernelGGL(rev_lstm_kernel, dim3(NP), dim3(256), 0, stream,
                       x, h0, c0, Wih, Whh, bih, bhh, out, ws);
}

// Round 9
// 9672.614 us; speedup vs baseline: 1.5619x; 1.0212x over previous
//
#include <hip/hip_runtime.h>
#include <hip/hip_bf16.h>
#include <stdint.h>

#define TT 2048
#define BB 32
#define II 256
#define HH 256
#define NP 16          // participating workgroups (grid size; w = blockIdx.x)
#define HW 16          // h-dims per participant (HH/NP)
#define LROW 264       // h_lds row stride in shorts (528B)
#define XROW 272       // x_lds row stride in shorts (544B)
#define ROUNDS_MAX (1 << 18)   // poll bound: fail-slow (visible), never silent

typedef __attribute__((ext_vector_type(8))) short short8;
typedef __attribute__((ext_vector_type(4))) float floatx4;

__device__ __forceinline__ short bf16r(float f) {
    __hip_bfloat16 b = __float2bfloat16(f);
    return *reinterpret_cast<short*>(&b);
}

// Exchange primitives (rounds 4/6/8 proven).
// Stores: compiler atomics at AGENT scope — memory-model-correct cache bits,
// visible device-wide at the LLC coherence point.
// Poll loads: 8x inline-asm dwordx4 with sc1 ONLY (= agent scope; round-5
// lesson: sc0+sc1 = system scope = bypasses LLC -> stale). One batched issue
// + one vmcnt wait per round. Tag-in-dword is ground truth: a stale/torn
// read fails the tag and re-polls — correctness never depends on timing.
// Round-9: s_sleep backoff between failed rounds. Theory: 4096 threads
// re-polling the same 32KB of LLC lines every ~0.35us keeps those banks'
// read queues full and starves the producers' WRITES to the same lines
// (store->visible measured ~4us >> 1 LLC RT). Backoff gives writes
// arbitration room; detection granularity only worsens by <=0.15us.
__device__ __forceinline__ void st_xch(unsigned* p, unsigned v) {
    __hip_atomic_store(p, v, __ATOMIC_RELAXED, __HIP_MEMORY_SCOPE_AGENT);
}
__device__ __forceinline__ uint4 ld4_agent(const unsigned* p) {
    uint4 r;
    asm volatile("global_load_dwordx4 %0, %1, off sc1" : "=v"(r) : "v"(p) : "memory");
    return r;
}
__device__ __forceinline__ void waitvm0() {
    asm volatile("s_waitcnt vmcnt(0)" ::: "memory");
}

// 16 WGs, one per worker w = blockIdx.x. Worker w owns h-dims [w*16,w*16+16)
// -> gate cols {g*256+w*16+j}. Weights register-stationary. x staged to LDS
// as bf16 one step ahead (double-buffered; cvt+write AFTER the exchange store
// so it overlaps the store flight, not the pre-gates critical path).
// h exchange: fused {t<<16|bf16(h)} dwords, double-buffered by t&1.
__global__ __launch_bounds__(256, 1)
void rev_lstm_kernel(const float* __restrict__ x,
                     const float* __restrict__ h0,
                     const float* __restrict__ c0,
                     const float* __restrict__ Wih,
                     const float* __restrict__ Whh,
                     const float* __restrict__ bih,
                     const float* __restrict__ bhh,
                     float* __restrict__ out,
                     unsigned int* __restrict__ ws)
{
    unsigned* xch = ws + 16;            // 2 * BB*HH tagged dwords (64 KB)

    __shared__ __align__(16) short h_lds[BB * LROW];
    __shared__ __align__(16) short x_lds[2][BB * XROW];   // bf16 x-tile dbuf
    __shared__ float gates_lds[4 * BB * HW];   // [gate][b][j]

    const int tid = threadIdx.x;
    const int w   = blockIdx.x;         // worker id, no election

    const int wid  = tid >> 6;          // wave id == gate id (i,f,g,o)
    const int lane = tid & 63;
    const int l15  = lane & 15;
    const int quad = lane >> 4;

    // staging mapping: thread owns (row = tid>>3, k-seg = tid&7 -> 32 k's)
    const int srow = tid >> 3, sseg = tid & 7;

    // ---- stationary weight B-fragments (B[k][n]: n=lane&15 -> col, k=quad*8+j)
    const int col = wid * HH + w * HW + l15;
    short8 wihf[8], whhf[8];
#pragma unroll
    for (int kt = 0; kt < 8; ++kt) {
        const int k0 = kt * 32 + quad * 8;
        const float* pi = Wih + (size_t)col * II + k0;
        const float* ph = Whh + (size_t)col * HH + k0;
        short8 a, b;
#pragma unroll
        for (int j = 0; j < 8; ++j) { a[j] = bf16r(pi[j]); b[j] = bf16r(ph[j]); }
        wihf[kt] = a; whhf[kt] = b;
    }
    const float bias = bih[col] + bhh[col];

    // ---- c state fp32; thread owns (b=jb, j=jj) and (b=jb+16, j=jj)
    const int jb = tid >> 4;
    const int jj = tid & 15;
    float creg0 = c0[(size_t)jb * HH + w * HW + jj];
    float creg1 = c0[(size_t)(jb + 16) * HH + w * HW + jj];

    // ---- prefill h_lds with h0 (fp32 -> bf16)
    const int pb = tid >> 3, pseg = tid & 7;     // poll/gather mapping
    {
        const float* src = h0 + (size_t)pb * HH + pseg * 32;
#pragma unroll
        for (int u = 0; u < 32; ++u) h_lds[pb * LROW + pseg * 32 + u] = bf16r(src[u]);
    }

    // ---- prologue: stage x_{TT-1} into x_lds[0]
    {
        const float* src = x + (size_t)(TT - 1) * (BB * II) + srow * II + sseg * 32;
        float4 f[8];
#pragma unroll
        for (int q = 0; q < 8; ++q) f[q] = *reinterpret_cast<const float4*>(src + q * 4);
        short* dst = &x_lds[0][srow * XROW + sseg * 32];
#pragma unroll
        for (int qq = 0; qq < 4; ++qq) {
            short8 s;
            s[0]=bf16r(f[2*qq].x);   s[1]=bf16r(f[2*qq].y);
            s[2]=bf16r(f[2*qq].z);   s[3]=bf16r(f[2*qq].w);
            s[4]=bf16r(f[2*qq+1].x); s[5]=bf16r(f[2*qq+1].y);
            s[6]=bf16r(f[2*qq+1].z); s[7]=bf16r(f[2*qq+1].w);
            *reinterpret_cast<short8*>(dst + qq * 8) = s;
        }
    }
    __syncthreads();

    int cur = 0;
    for (int t = TT - 1; t >= 0; --t) {
        // ---- 1. x-part from LDS: 16 ds_read_b128 + 16 MFMAs (no cvt)
        floatx4 acc0 = {bias, bias, bias, bias};
        floatx4 acc1 = {bias, bias, bias, bias};
        const short* xb = &x_lds[cur][0];
#pragma unroll
        for (int kt = 0; kt < 8; ++kt) {
            const int off = kt * 32 + quad * 8;
            short8 a = *reinterpret_cast<const short8*>(xb + l15 * XROW + off);
            short8 b = *reinterpret_cast<const short8*>(xb + (l15 + 16) * XROW + off);
            acc0 = __builtin_amdgcn_mfma_f32_16x16x32_bf16(a, wihf[kt], acc0, 0, 0, 0);
            acc1 = __builtin_amdgcn_mfma_f32_16x16x32_bf16(b, wihf[kt], acc1, 0, 0, 0);
        }

        // ---- 1b-issue. x_{t-1} loads ISSUED here; the first poll round's
        // vmcnt(0) drains them, so their HBM latency hides under the wait.
        float4 f[8];
        if (t > 0) {
            const float* src = x + (size_t)(t - 1) * (BB * II) + srow * II + sseg * 32;
#pragma unroll
            for (int q = 0; q < 8; ++q) f[q] = *reinterpret_cast<const float4*>(src + q * 4);
        }

        // ---- 2. poll tagged h_{t+1}: 8x dwordx4 sc1 (agent/LLC), one vmcnt
        // wait per round, s_sleep backoff between failed rounds.
        if (t != TT - 1) {
            const unsigned want = ((unsigned)(t + 1)) << 16;
            const unsigned* base = xch + (((unsigned)(t + 1)) & 1u) * (BB * HH)
                                       + pb * HH + pseg * 32;
            unsigned v[32];
            int rounds = 0;
            bool ok;
            do {
                if (rounds) __builtin_amdgcn_s_sleep(4);   // ~256cy backoff
                uint4 q[8];
#pragma unroll
                for (int i = 0; i < 8; ++i) q[i] = ld4_agent(base + i * 4);
                waitvm0();
#pragma unroll
                for (int i = 0; i < 8; ++i) {
                    v[i*4+0] = q[i].x; v[i*4+1] = q[i].y;
                    v[i*4+2] = q[i].z; v[i*4+3] = q[i].w;
                }
                unsigned bad = 0;
#pragma unroll
                for (int i = 0; i < 32; ++i)
                    bad |= (v[i] ^ want) & 0xFFFF0000u;   // XOR+OR-reduce check
                ok = (bad == 0u);
            } while (!ok && ++rounds < ROUNDS_MAX);

            // bf16 payloads -> LDS (packed pairs, 4x b128 writes)
#pragma unroll
            for (int q2 = 0; q2 < 4; ++q2) {
                uint4 d;
                d.x = (v[q2*8+0] & 0xFFFFu) | (v[q2*8+1] << 16);
                d.y = (v[q2*8+2] & 0xFFFFu) | (v[q2*8+3] << 16);
                d.z = (v[q2*8+4] & 0xFFFFu) | (v[q2*8+5] << 16);
                d.w = (v[q2*8+6] & 0xFFFFu) | (v[q2*8+7] << 16);
                *reinterpret_cast<uint4*>(h_lds + pb * LROW + pseg * 32 + q2 * 8) = d;
            }
            __syncthreads();                               // BARRIER-A
        }

        // ---- 3. recurrent MFMAs: += h@Whh^T  (straight from the barrier;
        // x staging no longer sits on this path)
#pragma unroll
        for (int kt = 0; kt < 8; ++kt) {
            const int off = kt * 32 + quad * 8;
            short8 ha0 = *reinterpret_cast<const short8*>(h_lds + l15 * LROW + off);
            short8 ha1 = *reinterpret_cast<const short8*>(h_lds + (l15 + 16) * LROW + off);
            acc0 = __builtin_amdgcn_mfma_f32_16x16x32_bf16(ha0, whhf[kt], acc0, 0, 0, 0);
            acc1 = __builtin_amdgcn_mfma_f32_16x16x32_bf16(ha1, whhf[kt], acc1, 0, 0, 0);
        }

        // ---- 4. accumulators -> LDS (C/D layout: col=lane&15, row=quad*4+r)
#pragma unroll
        for (int r = 0; r < 4; ++r) {
            gates_lds[(wid * BB + quad * 4 + r) * HW + l15]      = acc0[r];
            gates_lds[(wid * BB + 16 + quad * 4 + r) * HW + l15] = acc1[r];
        }
        __syncthreads();                                   // BARRIER-B

        // ---- 5. cell; tagged h -> exchange FIRST (critical path)
        float hval[2];
#pragma unroll
        for (int n = 0; n < 2; ++n) {
            const int b = jb + n * 16;
            const float ig = gates_lds[(0 * BB + b) * HW + jj];
            const float fg = gates_lds[(1 * BB + b) * HW + jj];
            const float gg = gates_lds[(2 * BB + b) * HW + jj];
            const float og = gates_lds[(3 * BB + b) * HW + jj];
            const float is = 1.f / (1.f + __expf(-ig));
            const float fs = 1.f / (1.f + __expf(-fg));
            const float gt = 1.f - 2.f / (1.f + __expf(2.f * gg));
            const float os = 1.f / (1.f + __expf(-og));
            const float cprev = (n == 0) ? creg0 : creg1;
            const float c  = fs * cprev + is * gt;
            const float h  = os * (1.f - 2.f / (1.f + __expf(2.f * c)));
            if (n == 0) creg0 = c; else creg1 = c;
            hval[n] = h;

            const unsigned pack = (((unsigned)t) << 16)
                                | (unsigned)(unsigned short)bf16r(h);
            st_xch(xch + ((unsigned)t & 1u) * (BB * HH) + (size_t)b * HH + w * HW + jj,
                   pack);
        }

        // ---- 6. x cvt + LDS-write (moved here: overlaps the exchange-store
        // flight instead of sitting between gather and h-MFMAs)
        if (t > 0) {
            short* dst = &x_lds[cur ^ 1][srow * XROW + sseg * 32];
#pragma unroll
            for (int qq = 0; qq < 4; ++qq) {
                short8 s;
                s[0]=bf16r(f[2*qq].x);   s[1]=bf16r(f[2*qq].y);
                s[2]=bf16r(f[2*qq].z);   s[3]=bf16r(f[2*qq].w);
                s[4]=bf16r(f[2*qq+1].x); s[5]=bf16r(f[2*qq+1].y);
                s[6]=bf16r(f[2*qq+1].z); s[7]=bf16r(f[2*qq+1].w);
                *reinterpret_cast<short8*>(dst + qq * 8) = s;
            }
        }

        // ---- 7. ys -> out (nontemporal), off the exchange critical path
#pragma unroll
        for (int n = 0; n < 2; ++n) {
            const int b = jb + n * 16;
            __builtin_nontemporal_store(hval[n], out + (size_t)t * (BB * HH)
                                                     + (size_t)b * HH + w * HW + jj);
            if (t == 0) {
                out[(size_t)TT * (BB * HH) + (size_t)b * HH + w * HW + jj] = hval[n];
                out[(size_t)TT * (BB * HH) + (BB * HH) + (size_t)b * HH + w * HW + jj]
                    = (n == 0) ? creg0 : creg1;
            }
        }

        __syncthreads();                                   // BARRIER-C: x_lds[cur^1]
        cur ^= 1;                                          // writes -> next-iter reads
        // Hazard audit: x_lds[new cur] write(S6,k) -> C -> read(S1,k+1) ok;
        // x_lds[other] last read (S1,k) precedes A/B/C before its next write
        // (S6,k+1) ok. gates_lds read(S5,k) -> C -> poll -> A -> write(S4,k+1)
        // ok. h_lds read(S3,k) -> B -> write(S2-gather,k+1 after A-spin) ok.
    }
}

extern "C" void kernel_launch(void* const* d_in, const int* in_sizes, int n_in,
                              void* d_out, int out_size, void* d_ws, size_t ws_size,
                              hipStream_t stream) {
    const float* x   = (const float*)d_in[0];
    const float* h0  = (const float*)d_in[1];
    const float* c0  = (const float*)d_in[2];
    const float* Wih = (const float*)d_in[3];
    const float* Whh = (const float*)d_in[4];
    const float* bih = (const float*)d_in[5];
    const float* bhh = (const float*)d_in[6];
    float* out = (float*)d_out;
    unsigned int* ws = (unsigned int*)d_ws;

    // xch tag bytes 0xAAAA never match a step tag (t+1 <= 2048 < 0xAAAA).
    hipMemsetAsync(ws, 0, 64, stream);
    hipMemsetAsync(ws + 16, 0xAA, 2 * BB * HH * sizeof(unsigned int), stream);
    hipLaunchKernelGGL(rev_lstm_kernel, dim3(NP), dim3(256), 0, stream,
                       x, h0, c0, Wih, Whh, bih, bhh, out, ws);
}